// Round 1
// baseline (557.492 us; speedup 1.0000x reference)
//
#include <hip/hip_runtime.h>
#include <math.h>

#define BLOCK 256
#define JS 16   // column slices per pass kernel (parallelism: 32x16=512 blocks)

__device__ __forceinline__ float fexp2(float x){
#if __has_builtin(__builtin_amdgcn_exp2f)
  return __builtin_amdgcn_exp2f(x);
#else
  return exp2f(x);
#endif
}

__device__ __forceinline__ float dot16(const float4& x0,const float4& x1,const float4& x2,const float4& x3,
                                       const float4& c0,const float4& c1,const float4& c2,const float4& c3){
  float d = x0.x*c0.x;
  d=fmaf(x0.y,c0.y,d); d=fmaf(x0.z,c0.z,d); d=fmaf(x0.w,c0.w,d);
  d=fmaf(x1.x,c1.x,d); d=fmaf(x1.y,c1.y,d); d=fmaf(x1.z,c1.z,d); d=fmaf(x1.w,c1.w,d);
  d=fmaf(x2.x,c2.x,d); d=fmaf(x2.y,c2.y,d); d=fmaf(x2.z,c2.z,d); d=fmaf(x2.w,c2.w,d);
  d=fmaf(x3.x,c3.x,d); d=fmaf(x3.y,c3.y,d); d=fmaf(x3.z,c3.z,d); d=fmaf(x3.w,c3.w,d);
  return d;
}

// consts[0] = kL = log2(e)/(4*softplus(log_eps));  consts[1] = t = softplus(log_t)
__global__ void consts_kernel(const float* __restrict__ le, const float* __restrict__ lt,
                              float* __restrict__ consts){
  if (threadIdx.x==0 && blockIdx.x==0){
    float a = le[0], b = lt[0];
    float eps = (a>0.f) ? a + log1pf(expf(-a)) : log1pf(expf(a));
    float t   = (b>0.f) ? b + log1pf(expf(-b)) : log1pf(expf(b));
    float cc = 0.25f/eps;
    consts[0] = cc * 1.44269504088896340736f;
    consts[1] = t;
  }
}

// pa = -kL*||row||^2 for X rows (pax) and Xref rows (pbr)
__global__ __launch_bounds__(BLOCK)
void norms_kernel(const float* __restrict__ X, const float* __restrict__ R,
                  const float* __restrict__ consts,
                  float* __restrict__ pax, float* __restrict__ pbr, int N, int M){
  int i = blockIdx.x*BLOCK + threadIdx.x;
  float kL = consts[0];
  const float* src; float* dst; int idx;
  if (i < N){ src = X; dst = pax; idx = i; }
  else if (i < N+M){ src = R; dst = pbr; idx = i-N; }
  else return;
  const float4* p = reinterpret_cast<const float4*>(src + (size_t)idx*16);
  float4 a=p[0], b=p[1], c=p[2], d=p[3];
  float s = a.x*a.x+a.y*a.y+a.z*a.z+a.w*a.w
          + b.x*b.x+b.y*b.y+b.z*b.z+b.w*b.w
          + c.x*c.x+c.y*c.y+c.z*c.z+c.w*c.w
          + d.x*d.x+d.y*d.y+d.z*d.z+d.w*d.w;
  dst[idx] = -kL*s;
}

// MODE 0: acc1 = sum_j w            (ref pass 1)
// MODE 1: acc2 = sum_j w*dref[j]    (ref pass 2)
// MODE 2: both                      (cross pass)
template<int MODE>
__global__ __launch_bounds__(BLOCK)
void pass_kernel(const float* __restrict__ A, const float* __restrict__ paA,
                 const float* __restrict__ R, const float* __restrict__ pbR,
                 const float* __restrict__ dref, const float* __restrict__ consts,
                 float* __restrict__ out1, float* __restrict__ out2,
                 int nrows, int M, int pstride)
{
  int row = blockIdx.x*BLOCK + threadIdx.x;
  if (row >= nrows) return;
  const float kL2 = 2.0f*consts[0];
  const float4* rp = reinterpret_cast<const float4*>(A + (size_t)row*16);
  float4 r0=rp[0], r1=rp[1], r2=rp[2], r3=rp[3];
  const float pa = paA[row];
  const int per = M/JS;
  const int j0 = blockIdx.y*per;
  float acc1 = 0.f, acc2 = 0.f;
  #pragma unroll 2
  for (int j=j0; j<j0+per; ++j){
    const float4* cp = reinterpret_cast<const float4*>(R + (size_t)j*16);
    float4 c0=cp[0], c1=cp[1], c2=cp[2], c3=cp[3];
    float dot = dot16(r0,r1,r2,r3, c0,c1,c2,c3);
    float arg = fminf(fmaf(kL2, dot, pa + pbR[j]), 0.f);
    float w = fexp2(arg);
    if (MODE != 1) acc1 += w;
    if (MODE >= 1) acc2 = fmaf(w, dref[j], acc2);
  }
  int o = blockIdx.y*pstride + row;
  if (MODE != 1) out1[o] = acc1;
  if (MODE >= 1) out2[o] = acc2;
}

__global__ __launch_bounds__(BLOCK)
void fin_ref1(const float* __restrict__ part, const float* __restrict__ consts,
              float* __restrict__ dref, int n, int pstride){
  int i = blockIdx.x*BLOCK + threadIdx.x;
  if (i>=n) return;
  float s=0.f;
  #pragma unroll
  for (int k=0;k<JS;++k) s += part[(size_t)k*pstride+i];
  float t = consts[1];
  dref[i] = exp2f(-t * log2f(s));   // s^(-t)
}

__global__ __launch_bounds__(BLOCK)
void fin_ref2(const float* __restrict__ part2, const float* __restrict__ dref,
              float* __restrict__ bref, int n, int pstride){
  int i = blockIdx.x*BLOCK + threadIdx.x;
  if (i>=n) return;
  float s2=0.f;
  #pragma unroll
  for (int k=0;k<JS;++k) s2 += part2[(size_t)k*pstride+i];
  float d = dref[i];
  float dinv1 = 1.f/sqrtf(d*s2);
  bref[i] = d*dinv1;
}

__global__ __launch_bounds__(BLOCK)
void fin_cross(const float* __restrict__ part1, const float* __restrict__ part2,
               const float* __restrict__ consts, float* __restrict__ ax,
               int n, int pstride){
  int i = blockIdx.x*BLOCK + threadIdx.x;
  if (i>=n) return;
  float s1=0.f, s2=0.f;
  #pragma unroll
  for (int k=0;k<JS;++k){ s1 += part1[(size_t)k*pstride+i]; s2 += part2[(size_t)k*pstride+i]; }
  float t = consts[1];
  float Dx = exp2f(-t * log2f(s1));    // s1^(-t)
  ax[i] = Dx / sqrtf(Dx*s2);           // Dx * (Dx*s2)^(-1/2)
}

// Each thread owns 4 consecutive columns (registers); loops over rows (uniform).
__global__ __launch_bounds__(BLOCK)
void out_kernel(const float* __restrict__ X, const float* __restrict__ pax,
                const float* __restrict__ ax, const float* __restrict__ R,
                const float* __restrict__ pbR, const float* __restrict__ bref,
                const float* __restrict__ consts, float* __restrict__ W,
                int N, int M, int rowsPer)
{
  int j0 = (blockIdx.x*BLOCK + threadIdx.x)*4;
  if (j0 >= M) return;
  const float kL2 = 2.0f*consts[0];
  float4 c0[4], c1[4], c2[4], c3[4]; float pb[4], bb[4];
  #pragma unroll
  for (int q=0;q<4;++q){
    const float4* cp = reinterpret_cast<const float4*>(R + (size_t)(j0+q)*16);
    c0[q]=cp[0]; c1[q]=cp[1]; c2[q]=cp[2]; c3[q]=cp[3];
    pb[q]=pbR[j0+q]; bb[q]=bref[j0+q];
  }
  int i0 = blockIdx.y*rowsPer;
  int i1 = i0+rowsPer; if (i1 > N) i1 = N;
  for (int i=i0;i<i1;++i){
    const float4* xp = reinterpret_cast<const float4*>(X + (size_t)i*16);
    float4 x0=xp[0], x1=xp[1], x2=xp[2], x3=xp[3];
    float pa = pax[i], a = ax[i];
    float o[4];
    #pragma unroll
    for (int q=0;q<4;++q){
      float dot = dot16(x0,x1,x2,x3, c0[q],c1[q],c2[q],c3[q]);
      float arg = fminf(fmaf(kL2, dot, pa + pb[q]), 0.f);
      o[q] = fexp2(arg)*bb[q]*a;
    }
    float4 ov = make_float4(o[0],o[1],o[2],o[3]);
    *reinterpret_cast<float4*>(W + (size_t)i*M + j0) = ov;
  }
}

extern "C" void kernel_launch(void* const* d_in, const int* in_sizes, int n_in,
                              void* d_out, int out_size, void* d_ws, size_t ws_size,
                              hipStream_t stream) {
  const float* X  = (const float*)d_in[0];
  const float* R  = (const float*)d_in[1];
  const float* le = (const float*)d_in[2];
  const float* lt = (const float*)d_in[3];
  float* W = (float*)d_out;
  const int N = in_sizes[0]/16;
  const int M = in_sizes[1]/16;
  const int mx = (N > M) ? N : M;

  float* ws     = (float*)d_ws;
  float* consts = ws;                   // 8 floats
  float* pax    = consts + 8;           // N
  float* pbr    = pax + N;              // M
  float* dref   = pbr + M;              // M
  float* bref   = dref + M;             // M
  float* ax     = bref + M;             // N
  float* part1  = ax + N;               // JS*mx
  float* part2  = part1 + (size_t)JS*mx;// JS*mx

  consts_kernel<<<1, 64, 0, stream>>>(le, lt, consts);

  int nb = (N + M + BLOCK - 1)/BLOCK;
  norms_kernel<<<nb, BLOCK, 0, stream>>>(X, R, consts, pax, pbr, N, M);

  // ref pass 1: Dref
  dim3 gref((M + BLOCK - 1)/BLOCK, JS);
  pass_kernel<0><<<gref, BLOCK, 0, stream>>>(R, pbr, R, pbr, nullptr, consts,
                                             part1, nullptr, M, M, mx);
  fin_ref1<<<(M + BLOCK - 1)/BLOCK, BLOCK, 0, stream>>>(part1, consts, dref, M, mx);

  // ref pass 2: Dinv1ref -> bref
  pass_kernel<1><<<gref, BLOCK, 0, stream>>>(R, pbr, R, pbr, dref, consts,
                                             nullptr, part2, M, M, mx);
  fin_ref2<<<(M + BLOCK - 1)/BLOCK, BLOCK, 0, stream>>>(part2, dref, bref, M, mx);

  // cross pass: Dx, Dinv1x -> ax
  dim3 gx((N + BLOCK - 1)/BLOCK, JS);
  pass_kernel<2><<<gx, BLOCK, 0, stream>>>(X, pax, R, pbr, dref, consts,
                                           part1, part2, N, M, mx);
  fin_cross<<<(N + BLOCK - 1)/BLOCK, BLOCK, 0, stream>>>(part1, part2, consts, ax, N, mx);

  // output
  const int rowsPer = 128;
  dim3 go(M/(BLOCK*4), (N + rowsPer - 1)/rowsPer);
  out_kernel<<<go, BLOCK, 0, stream>>>(X, pax, ax, R, pbr, bref, consts, W, N, M, rowsPer);
}

// Round 2
// 497.635 us; speedup vs baseline: 1.1203x; 1.1203x over previous
//
#include <hip/hip_runtime.h>
#include <math.h>

#define BLOCK 256
#define PER 256      // columns staged per pass-kernel block (16 KB LDS)
#define ROWS 128     // rows staged per out-kernel block (8 KB LDS)

static_assert(PER == BLOCK, "staging code assumes PER==BLOCK");

__device__ __forceinline__ float fexp2(float x){
#if __has_builtin(__builtin_amdgcn_exp2f)
  return __builtin_amdgcn_exp2f(x);
#else
  return exp2f(x);
#endif
}

// balanced-tree 16-element dot: 4 independent FMA chains + 2-level combine
__device__ __forceinline__ float dot16t(const float4& x0,const float4& x1,const float4& x2,const float4& x3,
                                        const float4& c0,const float4& c1,const float4& c2,const float4& c3){
  float d0 = x0.x*c0.x; d0=fmaf(x0.y,c0.y,d0); d0=fmaf(x0.z,c0.z,d0); d0=fmaf(x0.w,c0.w,d0);
  float d1 = x1.x*c1.x; d1=fmaf(x1.y,c1.y,d1); d1=fmaf(x1.z,c1.z,d1); d1=fmaf(x1.w,c1.w,d1);
  float d2 = x2.x*c2.x; d2=fmaf(x2.y,c2.y,d2); d2=fmaf(x2.z,c2.z,d2); d2=fmaf(x2.w,c2.w,d2);
  float d3 = x3.x*c3.x; d3=fmaf(x3.y,c3.y,d3); d3=fmaf(x3.z,c3.z,d3); d3=fmaf(x3.w,c3.w,d3);
  return (d0+d1)+(d2+d3);
}

// consts[0] = kL = log2(e)/(4*softplus(log_eps));  consts[1] = t = softplus(log_t)
__global__ void consts_kernel(const float* __restrict__ le, const float* __restrict__ lt,
                              float* __restrict__ consts){
  if (threadIdx.x==0 && blockIdx.x==0){
    float a = le[0], b = lt[0];
    float eps = (a>0.f) ? a + log1pf(expf(-a)) : log1pf(expf(a));
    float t   = (b>0.f) ? b + log1pf(expf(-b)) : log1pf(expf(b));
    float cc = 0.25f/eps;
    consts[0] = cc * 1.44269504088896340736f;
    consts[1] = t;
  }
}

// pa = -kL*||row||^2 for X rows (pax) and Xref rows (pbr)
__global__ __launch_bounds__(BLOCK)
void norms_kernel(const float* __restrict__ X, const float* __restrict__ R,
                  const float* __restrict__ consts,
                  float* __restrict__ pax, float* __restrict__ pbr, int N, int M){
  int i = blockIdx.x*BLOCK + threadIdx.x;
  float kL = consts[0];
  const float* src; float* dst; int idx;
  if (i < N){ src = X; dst = pax; idx = i; }
  else if (i < N+M){ src = R; dst = pbr; idx = i-N; }
  else return;
  const float4* p = reinterpret_cast<const float4*>(src + (size_t)idx*16);
  float4 a=p[0], b=p[1], c=p[2], d=p[3];
  float s = a.x*a.x+a.y*a.y+a.z*a.z+a.w*a.w
          + b.x*b.x+b.y*b.y+b.z*b.z+b.w*b.w
          + c.x*c.x+c.y*c.y+c.z*c.z+c.w*c.w
          + d.x*d.x+d.y*d.y+d.z*d.z+d.w*d.w;
  dst[idx] = -kL*s;
}

// MODE 0: acc1 = sum_j w            (ref pass 1)
// MODE 1: acc2 = sum_j w*dref[j]    (ref pass 2)
// MODE 2: both                      (cross pass)
// Column slice [j0, j0+PER) staged in LDS; inner loop reads broadcast LDS.
template<int MODE>
__global__ __launch_bounds__(BLOCK)
void pass_kernel(const float* __restrict__ A, const float* __restrict__ paA,
                 const float* __restrict__ R, const float* __restrict__ pbR,
                 const float* __restrict__ dref, const float* __restrict__ consts,
                 float* __restrict__ out1, float* __restrict__ out2,
                 int nrows, int pstride)
{
  __shared__ float4 sC[PER*4];   // column j at sC[j*4 .. j*4+3]
  __shared__ float  sB[PER];     // pbR slice
  __shared__ float  sD[PER];     // dref slice (MODE>=1)
  const int j0 = blockIdx.y*PER;

  const float4* gsrc = reinterpret_cast<const float4*>(R + (size_t)j0*16);
  #pragma unroll
  for (int k=0;k<(PER*4)/BLOCK;++k)
    sC[threadIdx.x + k*BLOCK] = gsrc[threadIdx.x + k*BLOCK];
  sB[threadIdx.x] = pbR[j0 + threadIdx.x];
  if (MODE >= 1) sD[threadIdx.x] = dref[j0 + threadIdx.x];
  __syncthreads();

  const int row = blockIdx.x*BLOCK + threadIdx.x;
  if (row >= nrows) return;
  const float kL2 = 2.0f*consts[0];
  const float4* rp = reinterpret_cast<const float4*>(A + (size_t)row*16);
  float4 r0=rp[0], r1=rp[1], r2=rp[2], r3=rp[3];
  const float pa = paA[row];

  float acc1 = 0.f, acc2 = 0.f;
  #pragma unroll 4
  for (int jj=0; jj<PER; ++jj){
    float4 c0=sC[jj*4+0], c1=sC[jj*4+1], c2=sC[jj*4+2], c3=sC[jj*4+3];
    float dot = dot16t(r0,r1,r2,r3, c0,c1,c2,c3);
    float arg = fminf(fmaf(kL2, dot, pa + sB[jj]), 0.f);
    float w = fexp2(arg);
    if (MODE != 1) acc1 += w;
    if (MODE >= 1) acc2 = fmaf(w, sD[jj], acc2);
  }
  const int o = blockIdx.y*pstride + row;
  if (MODE != 1) out1[o] = acc1;
  if (MODE >= 1) out2[o] = acc2;
}

__global__ __launch_bounds__(BLOCK)
void fin_ref1(const float* __restrict__ part, const float* __restrict__ consts,
              float* __restrict__ dref, int n, int pstride, int nsl){
  int i = blockIdx.x*BLOCK + threadIdx.x;
  if (i>=n) return;
  float s=0.f;
  for (int k=0;k<nsl;++k) s += part[(size_t)k*pstride+i];
  float t = consts[1];
  dref[i] = exp2f(-t * log2f(s));   // s^(-t)
}

__global__ __launch_bounds__(BLOCK)
void fin_ref2(const float* __restrict__ part2, const float* __restrict__ dref,
              float* __restrict__ bref, int n, int pstride, int nsl){
  int i = blockIdx.x*BLOCK + threadIdx.x;
  if (i>=n) return;
  float s2=0.f;
  for (int k=0;k<nsl;++k) s2 += part2[(size_t)k*pstride+i];
  float d = dref[i];
  bref[i] = d / sqrtf(d*s2);        // Dref * Dinv1ref
}

__global__ __launch_bounds__(BLOCK)
void fin_cross(const float* __restrict__ part1, const float* __restrict__ part2,
               const float* __restrict__ consts, float* __restrict__ ax,
               int n, int pstride, int nsl){
  int i = blockIdx.x*BLOCK + threadIdx.x;
  if (i>=n) return;
  float s1=0.f, s2=0.f;
  for (int k=0;k<nsl;++k){ s1 += part1[(size_t)k*pstride+i]; s2 += part2[(size_t)k*pstride+i]; }
  float t = consts[1];
  float Dx = exp2f(-t * log2f(s1)); // s1^(-t)
  ax[i] = Dx / sqrtf(Dx*s2);        // Dx * Dinv1x
}

// Thread owns 4 consecutive columns (in registers); rows staged in LDS.
__global__ __launch_bounds__(BLOCK)
void out_kernel(const float* __restrict__ X, const float* __restrict__ pax,
                const float* __restrict__ ax, const float* __restrict__ R,
                const float* __restrict__ pbR, const float* __restrict__ bref,
                const float* __restrict__ consts, float* __restrict__ W,
                int N, int M)
{
  __shared__ float4 sX[ROWS*4];   // row i at sX[i*4 .. i*4+3]
  __shared__ float  sPA[ROWS];
  __shared__ float  sA[ROWS];
  const int i0 = blockIdx.y*ROWS;

  const float4* gsrc = reinterpret_cast<const float4*>(X + (size_t)i0*16);
  #pragma unroll
  for (int k=0;k<(ROWS*4)/BLOCK;++k)
    sX[threadIdx.x + k*BLOCK] = gsrc[threadIdx.x + k*BLOCK];
  if (threadIdx.x < ROWS){
    sPA[threadIdx.x] = pax[i0 + threadIdx.x];
    sA[threadIdx.x]  = ax[i0 + threadIdx.x];
  }
  __syncthreads();

  const int j0 = (blockIdx.x*BLOCK + threadIdx.x)*4;
  const float kL2 = 2.0f*consts[0];
  float4 c0[4], c1[4], c2[4], c3[4]; float pb[4], bb[4];
  #pragma unroll
  for (int q=0;q<4;++q){
    const float4* cp = reinterpret_cast<const float4*>(R + (size_t)(j0+q)*16);
    c0[q]=cp[0]; c1[q]=cp[1]; c2[q]=cp[2]; c3[q]=cp[3];
    pb[q]=pbR[j0+q]; bb[q]=bref[j0+q];
  }

  #pragma unroll 2
  for (int ii=0; ii<ROWS; ++ii){
    float4 x0=sX[ii*4+0], x1=sX[ii*4+1], x2=sX[ii*4+2], x3=sX[ii*4+3];
    float pa = sPA[ii], a = sA[ii];
    float o[4];
    #pragma unroll
    for (int q=0;q<4;++q){
      float dot = dot16t(x0,x1,x2,x3, c0[q],c1[q],c2[q],c3[q]);
      float arg = fminf(fmaf(kL2, dot, pa + pb[q]), 0.f);
      o[q] = fexp2(arg)*bb[q]*a;
    }
    *reinterpret_cast<float4*>(W + (size_t)(i0+ii)*M + j0) =
        make_float4(o[0],o[1],o[2],o[3]);
  }
}

extern "C" void kernel_launch(void* const* d_in, const int* in_sizes, int n_in,
                              void* d_out, int out_size, void* d_ws, size_t ws_size,
                              hipStream_t stream) {
  const float* X  = (const float*)d_in[0];
  const float* R  = (const float*)d_in[1];
  const float* le = (const float*)d_in[2];
  const float* lt = (const float*)d_in[3];
  float* W = (float*)d_out;
  const int N = in_sizes[0]/16;
  const int M = in_sizes[1]/16;
  const int mx = (N > M) ? N : M;
  const int JS = M/PER;           // column slices (=32 for M=8192)

  float* ws     = (float*)d_ws;
  float* consts = ws;                    // 8 floats
  float* pax    = consts + 8;            // N
  float* pbr    = pax + N;               // M
  float* dref   = pbr + M;               // M
  float* bref   = dref + M;              // M
  float* ax     = bref + M;              // N
  float* part1  = ax + N;                // JS*mx
  float* part2  = part1 + (size_t)JS*mx; // JS*mx

  consts_kernel<<<1, 64, 0, stream>>>(le, lt, consts);

  int nb = (N + M + BLOCK - 1)/BLOCK;
  norms_kernel<<<nb, BLOCK, 0, stream>>>(X, R, consts, pax, pbr, N, M);

  // ref pass 1: Dref
  dim3 gref((M + BLOCK - 1)/BLOCK, JS);
  pass_kernel<0><<<gref, BLOCK, 0, stream>>>(R, pbr, R, pbr, nullptr, consts,
                                             part1, nullptr, M, mx);
  fin_ref1<<<(M + BLOCK - 1)/BLOCK, BLOCK, 0, stream>>>(part1, consts, dref, M, mx, JS);

  // ref pass 2: Dinv1ref -> bref (= Dref*Dinv1ref)
  pass_kernel<1><<<gref, BLOCK, 0, stream>>>(R, pbr, R, pbr, dref, consts,
                                             nullptr, part2, M, mx);
  fin_ref2<<<(M + BLOCK - 1)/BLOCK, BLOCK, 0, stream>>>(part2, dref, bref, M, mx, JS);

  // cross pass: Dx, Dinv1x -> ax (= Dx*Dinv1x)
  dim3 gx((N + BLOCK - 1)/BLOCK, JS);
  pass_kernel<2><<<gx, BLOCK, 0, stream>>>(X, pax, R, pbr, dref, consts,
                                           part1, part2, N, mx);
  fin_cross<<<(N + BLOCK - 1)/BLOCK, BLOCK, 0, stream>>>(part1, part2, consts, ax, N, mx, JS);

  // output: grid (M/1024, N/ROWS)
  dim3 go(M/(BLOCK*4), (N + ROWS - 1)/ROWS);
  out_kernel<<<go, BLOCK, 0, stream>>>(X, pax, ax, R, pbr, bref, consts, W, N, M);
}

// Round 3
// 440.806 us; speedup vs baseline: 1.2647x; 1.1289x over previous
//
#include <hip/hip_runtime.h>
#include <math.h>

#define BLOCK 256
#define RT    8     // rows per thread in pass kernels
#define PER   64    // columns staged per pass-kernel block
#define CT    8     // columns per thread in out kernel
#define OROWS 64    // rows staged per out-kernel block

__device__ __forceinline__ float fexp2(float x){
#if __has_builtin(__builtin_amdgcn_exp2f)
  return __builtin_amdgcn_exp2f(x);
#else
  return exp2f(x);
#endif
}

// balanced-tree 16-element dot: 4 independent FMA chains + 2-level combine
__device__ __forceinline__ float dot16t(const float4& x0,const float4& x1,const float4& x2,const float4& x3,
                                        const float4& c0,const float4& c1,const float4& c2,const float4& c3){
  float d0 = x0.x*c0.x; d0=fmaf(x0.y,c0.y,d0); d0=fmaf(x0.z,c0.z,d0); d0=fmaf(x0.w,c0.w,d0);
  float d1 = x1.x*c1.x; d1=fmaf(x1.y,c1.y,d1); d1=fmaf(x1.z,c1.z,d1); d1=fmaf(x1.w,c1.w,d1);
  float d2 = x2.x*c2.x; d2=fmaf(x2.y,c2.y,d2); d2=fmaf(x2.z,c2.z,d2); d2=fmaf(x2.w,c2.w,d2);
  float d3 = x3.x*c3.x; d3=fmaf(x3.y,c3.y,d3); d3=fmaf(x3.z,c3.z,d3); d3=fmaf(x3.w,c3.w,d3);
  return (d0+d1)+(d2+d3);
}

// consts[0] = kL = log2(e)/(4*softplus(log_eps));  consts[1] = t = softplus(log_t)
__global__ void consts_kernel(const float* __restrict__ le, const float* __restrict__ lt,
                              float* __restrict__ consts){
  if (threadIdx.x==0 && blockIdx.x==0){
    float a = le[0], b = lt[0];
    float eps = (a>0.f) ? a + log1pf(expf(-a)) : log1pf(expf(a));
    float t   = (b>0.f) ? b + log1pf(expf(-b)) : log1pf(expf(b));
    consts[0] = (0.25f/eps) * 1.44269504088896340736f;
    consts[1] = t;
  }
}

__global__ __launch_bounds__(BLOCK)
void zero_kernel(float* __restrict__ p, int n){
  int i = blockIdx.x*BLOCK + threadIdx.x;
  if (i < n) p[i] = 0.f;
}

// pa = -kL*||row||^2 for X rows (pax) and Xref rows (pbr)
__global__ __launch_bounds__(BLOCK)
void norms_kernel(const float* __restrict__ X, const float* __restrict__ R,
                  const float* __restrict__ consts,
                  float* __restrict__ pax, float* __restrict__ pbr, int N, int M){
  int i = blockIdx.x*BLOCK + threadIdx.x;
  float kL = consts[0];
  const float* src; float* dst; int idx;
  if (i < N){ src = X; dst = pax; idx = i; }
  else if (i < N+M){ src = R; dst = pbr; idx = i-N; }
  else return;
  const float4* p = reinterpret_cast<const float4*>(src + (size_t)idx*16);
  float4 a=p[0], b=p[1], c=p[2], d=p[3];
  float s = a.x*a.x+a.y*a.y+a.z*a.z+a.w*a.w
          + b.x*b.x+b.y*b.y+b.z*b.z+b.w*b.w
          + c.x*c.x+c.y*c.y+c.z*c.z+c.w*c.w
          + d.x*d.x+d.y*d.y+d.z*d.z+d.w*d.w;
  dst[idx] = -kL*s;
}

// MODE 0: sum1 += w ; MODE 1: sum2 += w*dref ; MODE 2: both.
// 8 rows/thread in VGPRs; column slice broadcast from LDS (amortized 8x).
template<int MODE>
__global__ __launch_bounds__(BLOCK, 2)
void pass_kernel(const float* __restrict__ A, const float* __restrict__ paA,
                 const float* __restrict__ R, const float* __restrict__ pbR,
                 const float* __restrict__ dref, const float* __restrict__ consts,
                 float* __restrict__ sum1, float* __restrict__ sum2,
                 int nrows, int M)
{
  __shared__ float4 sC[PER][4];
  __shared__ float2 sE[PER];    // (pb, dref)
  const int t  = threadIdx.x;
  const int j0 = blockIdx.y*PER;
  const int jmax = (M - j0 < PER) ? (M - j0) : PER;

  { // stage 64 cols x 4 float4 = 256 loads
    int col = t>>2, q = t&3;
    int jc = j0 + col; if (jc >= M) jc = M-1;
    sC[col][q] = reinterpret_cast<const float4*>(R + (size_t)jc*16)[q];
    if (t < PER){
      int j = j0 + t; if (j >= M) j = M-1;
      float d = (MODE>=1) ? dref[j] : 0.f;
      sE[t] = make_float2(pbR[j], d);
    }
  }
  __syncthreads();

  const float kL2 = 2.0f*consts[0];
  const int rbase = blockIdx.x*(BLOCK*RT);

  float4 r[RT][4]; float pa[RT]; float acc1[RT], acc2[RT];
  #pragma unroll
  for (int k=0;k<RT;++k){
    int row = rbase + k*BLOCK + t; if (row >= nrows) row = nrows-1;
    const float4* rp = reinterpret_cast<const float4*>(A + (size_t)row*16);
    r[k][0]=rp[0]; r[k][1]=rp[1]; r[k][2]=rp[2]; r[k][3]=rp[3];
    pa[k] = paA[row];
    acc1[k]=0.f; acc2[k]=0.f;
  }

  for (int jj=0; jj<jmax; ++jj){
    float4 c0=sC[jj][0], c1=sC[jj][1], c2=sC[jj][2], c3=sC[jj][3];
    float2 e = sE[jj];
    #pragma unroll
    for (int k=0;k<RT;++k){
      float dot = dot16t(r[k][0],r[k][1],r[k][2],r[k][3], c0,c1,c2,c3);
      float arg = fminf(fmaf(kL2, dot, pa[k] + e.x), 0.f);
      float w = fexp2(arg);
      if (MODE != 1) acc1[k] += w;
      if (MODE >= 1) acc2[k] = fmaf(w, e.y, acc2[k]);
    }
  }
  #pragma unroll
  for (int k=0;k<RT;++k){
    int row = rbase + k*BLOCK + t;
    if (row < nrows){
      if (MODE != 1) atomicAdd(&sum1[row], acc1[k]);
      if (MODE >= 1) atomicAdd(&sum2[row], acc2[k]);
    }
  }
}

__global__ __launch_bounds__(BLOCK)
void fin_ref1(const float* __restrict__ s1, const float* __restrict__ consts,
              float* __restrict__ dref, int n){
  int i = blockIdx.x*BLOCK + threadIdx.x;
  if (i>=n) return;
  float t = consts[1];
  dref[i] = exp2f(-t * log2f(s1[i]));      // s^(-t)
}

__global__ __launch_bounds__(BLOCK)
void fin_ref2(const float* __restrict__ s2, const float* __restrict__ dref,
              float* __restrict__ bref, int n){
  int i = blockIdx.x*BLOCK + threadIdx.x;
  if (i>=n) return;
  float d = dref[i];
  bref[i] = d / sqrtf(d*s2[i]);            // Dref*Dinv1ref
}

__global__ __launch_bounds__(BLOCK)
void fin_cross(const float* __restrict__ s1, const float* __restrict__ s2,
               const float* __restrict__ consts, float* __restrict__ ax, int n){
  int i = blockIdx.x*BLOCK + threadIdx.x;
  if (i>=n) return;
  float t = consts[1];
  float Dx = exp2f(-t * log2f(s1[i]));     // s1^(-t)
  ax[i] = Dx / sqrtf(Dx*s2[i]);            // Dx*Dinv1x
}

// 8 cols/thread in VGPRs (t*4 and t*4+1024 for coalesced stores);
// rows broadcast from LDS (amortized 8x).
__global__ __launch_bounds__(BLOCK, 2)
void out_kernel(const float* __restrict__ X, const float* __restrict__ pax,
                const float* __restrict__ ax, const float* __restrict__ R,
                const float* __restrict__ pbR, const float* __restrict__ bref,
                const float* __restrict__ consts, float* __restrict__ W,
                int N, int M)
{
  __shared__ float4 sX[OROWS][4];
  __shared__ float2 sE[OROWS];   // (pa, ax)
  const int t  = threadIdx.x;
  const int i0 = blockIdx.y*OROWS;

  {
    int rr = t>>2, q = t&3;
    int ir = i0 + rr; if (ir >= N) ir = N-1;
    sX[rr][q] = reinterpret_cast<const float4*>(X + (size_t)ir*16)[q];
    if (t < OROWS){
      int i = i0 + t; if (i >= N) i = N-1;
      sE[t] = make_float2(pax[i], ax[i]);
    }
  }
  __syncthreads();

  const float kL2 = 2.0f*consts[0];
  const int j0a = blockIdx.x*(BLOCK*CT) + t*4;   // cols j0a..j0a+3
  const int j0b = j0a + BLOCK*4;                 // cols j0b..j0b+3

  float4 c[CT][4]; float pbb[CT], bb[CT];
  #pragma unroll
  for (int q=0;q<CT;++q){
    int jc = (q<4) ? (j0a+q) : (j0b+q-4); if (jc >= M) jc = M-1;
    const float4* cp = reinterpret_cast<const float4*>(R + (size_t)jc*16);
    c[q][0]=cp[0]; c[q][1]=cp[1]; c[q][2]=cp[2]; c[q][3]=cp[3];
    pbb[q]=pbR[jc]; bb[q]=bref[jc];
  }

  const int imax = (N - i0 < OROWS) ? (N - i0) : OROWS;
  for (int ii=0; ii<imax; ++ii){
    float4 x0=sX[ii][0], x1=sX[ii][1], x2=sX[ii][2], x3=sX[ii][3];
    float2 e = sE[ii];
    float o[CT];
    #pragma unroll
    for (int q=0;q<CT;++q){
      float dot = dot16t(x0,x1,x2,x3, c[q][0],c[q][1],c[q][2],c[q][3]);
      float arg = fminf(fmaf(kL2, dot, e.x + pbb[q]), 0.f);
      o[q] = fexp2(arg)*(bb[q]*e.y);
    }
    float* wp = W + (size_t)(i0+ii)*M;
    if (j0a+3 < M) *reinterpret_cast<float4*>(wp + j0a) = make_float4(o[0],o[1],o[2],o[3]);
    if (j0b+3 < M) *reinterpret_cast<float4*>(wp + j0b) = make_float4(o[4],o[5],o[6],o[7]);
  }
}

extern "C" void kernel_launch(void* const* d_in, const int* in_sizes, int n_in,
                              void* d_out, int out_size, void* d_ws, size_t ws_size,
                              hipStream_t stream) {
  const float* X  = (const float*)d_in[0];
  const float* R  = (const float*)d_in[1];
  const float* le = (const float*)d_in[2];
  const float* lt = (const float*)d_in[3];
  float* W = (float*)d_out;
  const int N = in_sizes[0]/16;
  const int M = in_sizes[1]/16;

  float* ws     = (float*)d_ws;
  float* consts = ws;              // 8
  float* pax    = consts + 8;      // N
  float* pbr    = pax + N;         // M
  float* dref   = pbr + M;         // M
  float* bref   = dref + M;        // M
  float* ax     = bref + M;        // N
  float* s1r    = ax + N;          // M   (zeroed)
  float* s2r    = s1r + M;         // M   (zeroed)
  float* s1x    = s2r + M;         // N   (zeroed)
  float* s2x    = s1x + N;         // N   (zeroed)

  consts_kernel<<<1, 64, 0, stream>>>(le, lt, consts);

  const int nz = 2*M + 2*N;
  zero_kernel<<<(nz + BLOCK-1)/BLOCK, BLOCK, 0, stream>>>(s1r, nz);

  norms_kernel<<<(N + M + BLOCK-1)/BLOCK, BLOCK, 0, stream>>>(X, R, consts, pax, pbr, N, M);

  const int gslice = (M + PER - 1)/PER;                 // 128
  const int grref  = (M + BLOCK*RT - 1)/(BLOCK*RT);     // 4
  const int grx    = (N + BLOCK*RT - 1)/(BLOCK*RT);     // 4

  // ref pass 1: Dref
  pass_kernel<0><<<dim3(grref, gslice), BLOCK, 0, stream>>>(R, pbr, R, pbr, nullptr, consts,
                                                            s1r, nullptr, M, M);
  fin_ref1<<<(M + BLOCK-1)/BLOCK, BLOCK, 0, stream>>>(s1r, consts, dref, M);

  // ref pass 2: bref = Dref*Dinv1ref
  pass_kernel<1><<<dim3(grref, gslice), BLOCK, 0, stream>>>(R, pbr, R, pbr, dref, consts,
                                                            nullptr, s2r, M, M);
  fin_ref2<<<(M + BLOCK-1)/BLOCK, BLOCK, 0, stream>>>(s2r, dref, bref, M);

  // cross pass: ax = Dx*Dinv1x
  pass_kernel<2><<<dim3(grx, gslice), BLOCK, 0, stream>>>(X, pax, R, pbr, dref, consts,
                                                          s1x, s2x, N, M);
  fin_cross<<<(N + BLOCK-1)/BLOCK, BLOCK, 0, stream>>>(s1x, s2x, consts, ax, N);

  // output
  dim3 go((M + BLOCK*CT - 1)/(BLOCK*CT), (N + OROWS - 1)/OROWS);  // (4, 128)
  out_kernel<<<go, BLOCK, 0, stream>>>(X, pax, ax, R, pbr, bref, consts, W, N, M);
}

// Round 4
// 351.460 us; speedup vs baseline: 1.5862x; 1.2542x over previous
//
#include <hip/hip_runtime.h>
#include <math.h>

#define BLOCK 256
#define CPC 512           // cols per chunk in pass kernels (32 tiles)
#define CPCO 512          // cols per chunk in out kernel

typedef __attribute__((ext_vector_type(8))) short bf16x8;
typedef __attribute__((ext_vector_type(4))) float f32x4;
typedef unsigned int u32;

__device__ __forceinline__ float fexp2(float x){
#if __has_builtin(__builtin_amdgcn_exp2f)
  return __builtin_amdgcn_exp2f(x);
#else
  return exp2f(x);
#endif
}

__device__ __forceinline__ u32 rne16(float f){   // round-to-nearest-even bf16 (finite inputs)
  u32 u = __float_as_uint(f);
  return (u + 0x7FFFu + ((u>>16)&1u)) >> 16;
}

// consts[0]=kappa (log2-scaled), consts[1]=t, consts[2]=s=sqrt(2*kappa)
__global__ void consts_kernel(const float* __restrict__ le, const float* __restrict__ lt,
                              float* __restrict__ consts){
  if (threadIdx.x==0 && blockIdx.x==0){
    float a = le[0], b = lt[0];
    float eps = (a>0.f) ? a + log1pf(expf(-a)) : log1pf(expf(a));
    float t   = (b>0.f) ? b + log1pf(expf(-b)) : log1pf(expf(b));
    float kappa = (0.25f/eps) * 1.44269504088896340736f;  // inv_scale2 * log2(e)
    consts[0] = kappa;
    consts[1] = t;
    consts[2] = sqrtf(2.0f*kappa);
  }
}

__global__ __launch_bounds__(BLOCK)
void zero_kernel(float* __restrict__ p, int n){
  int i = blockIdx.x*BLOCK + threadIdx.x;
  if (i < n) p[i] = 0.f;
}

// Pack each point into split-bf16: words 0-7 = hi(16 elems), 8-15 = lo(16 elems),
// of y = s*x. Also pa = -0.5*|y|^2 (so c = pa+pb+y_a.y_b = -kappa*|a-b|^2, log2 units).
__global__ __launch_bounds__(BLOCK)
void prep_kernel(const float* __restrict__ X, const float* __restrict__ R,
                 const float* __restrict__ consts,
                 u32* __restrict__ PX, u32* __restrict__ PR,
                 float* __restrict__ pax, float* __restrict__ pbr, int N, int M){
  int i = blockIdx.x*BLOCK + threadIdx.x;
  const float s = consts[2];
  const float* src; u32* dst; float* pdst; int idx;
  if (i < N){ src=X; dst=PX; pdst=pax; idx=i; }
  else if (i < N+M){ src=R; dst=PR; pdst=pbr; idx=i-N; }
  else return;
  float y[16];
  const float4* p = reinterpret_cast<const float4*>(src + (size_t)idx*16);
  #pragma unroll
  for (int q=0;q<4;++q){
    float4 v = p[q];
    y[4*q+0]=s*v.x; y[4*q+1]=s*v.y; y[4*q+2]=s*v.z; y[4*q+3]=s*v.w;
  }
  float nrm = 0.f;
  #pragma unroll
  for (int k=0;k<16;++k) nrm = fmaf(y[k],y[k],nrm);
  u32 hw[16], lw[16];
  #pragma unroll
  for (int k=0;k<16;++k){
    u32 h16 = rne16(y[k]);
    float hf = __uint_as_float(h16<<16);
    float lo = y[k]-hf;                 // exact in fp32
    hw[k]=h16; lw[k]=rne16(lo);
  }
  uint4* dd = reinterpret_cast<uint4*>(dst + (size_t)idx*16);
  dd[0]=make_uint4(hw[0]|(hw[1]<<16),  hw[2]|(hw[3]<<16),  hw[4]|(hw[5]<<16),  hw[6]|(hw[7]<<16));
  dd[1]=make_uint4(hw[8]|(hw[9]<<16),  hw[10]|(hw[11]<<16),hw[12]|(hw[13]<<16),hw[14]|(hw[15]<<16));
  dd[2]=make_uint4(lw[0]|(lw[1]<<16),  lw[2]|(lw[3]<<16),  lw[4]|(lw[5]<<16),  lw[6]|(lw[7]<<16));
  dd[3]=make_uint4(lw[8]|(lw[9]<<16),  lw[10]|(lw[11]<<16),lw[12]|(lw[13]<<16),lw[14]|(lw[15]<<16));
  pdst[idx] = -0.5f*nrm;
}

// MFMA pass. Wave owns 2 row-strips of 16 (rb..rb+31), sweeps a col chunk.
// A-frag = [hi|lo] of row; B1 = [hi|hi], B2 = [lo|lo] of col -> c = full-precision
// scaled Gram + pa + pb after 2 chained MFMAs. w = exp2(c).
// MODE 0: sum1 += w ; MODE 1: sum2 += w*dref ; MODE 2: both.
template<int MODE>
__global__ __launch_bounds__(BLOCK)
void pass_mfma(const u32* __restrict__ PA, const float* __restrict__ paA,
               const u32* __restrict__ PB, const float* __restrict__ pbB,
               const float* __restrict__ dref,
               float* __restrict__ sum1, float* __restrict__ sum2)
{
  const int t=threadIdx.x, wv=t>>6, l=t&63, g=l>>4, c16=l&15;
  const int rb = (blockIdx.x*4 + wv)*32;
  const int j0 = blockIdx.y*CPC;

  bf16x8 a0 = *reinterpret_cast<const bf16x8*>(PA + (size_t)(rb+c16)*16    + g*4);
  bf16x8 a1 = *reinterpret_cast<const bf16x8*>(PA + (size_t)(rb+16+c16)*16 + g*4);
  float pa0[4], pa1[4];
  #pragma unroll
  for (int i=0;i<4;++i){ pa0[i]=paA[rb+4*g+i]; pa1[i]=paA[rb+16+4*g+i]; }

  const u32* pb1 = PB + (size_t)(j0+c16)*16 + (g&1)*4;   // hi half; lo at +8
  const float* ppb = pbB + j0 + c16;
  const float* pdr = dref + j0 + c16;

  f32x4 z1a={0,0,0,0}, z1b={0,0,0,0}, z2a={0,0,0,0}, z2b={0,0,0,0};

  #pragma unroll 2
  for (int tl=0; tl<CPC/16; ++tl){
    bf16x8 b1 = *reinterpret_cast<const bf16x8*>(pb1);
    bf16x8 b2 = *reinterpret_cast<const bf16x8*>(pb1 + 8);
    float pb = *ppb;
    float dr = (MODE>=1) ? *pdr : 0.f;

    f32x4 c0; c0[0]=pa0[0]+pb; c0[1]=pa0[1]+pb; c0[2]=pa0[2]+pb; c0[3]=pa0[3]+pb;
    c0 = __builtin_amdgcn_mfma_f32_16x16x32_bf16(a0,b1,c0,0,0,0);
    c0 = __builtin_amdgcn_mfma_f32_16x16x32_bf16(a0,b2,c0,0,0,0);
    f32x4 c1; c1[0]=pa1[0]+pb; c1[1]=pa1[1]+pb; c1[2]=pa1[2]+pb; c1[3]=pa1[3]+pb;
    c1 = __builtin_amdgcn_mfma_f32_16x16x32_bf16(a1,b1,c1,0,0,0);
    c1 = __builtin_amdgcn_mfma_f32_16x16x32_bf16(a1,b2,c1,0,0,0);

    #pragma unroll
    for (int i=0;i<4;++i){
      float w0 = fexp2(c0[i]);
      float w1 = fexp2(c1[i]);
      if (MODE!=1){ z1a[i]+=w0; z1b[i]+=w1; }
      if (MODE>=1){ z2a[i]=fmaf(w0,dr,z2a[i]); z2b[i]=fmaf(w1,dr,z2b[i]); }
    }
    pb1 += 256; ppb += 16; pdr += 16;
  }

  // reduce over the 16 columns (lanes sharing g): xor 1,2,4,8
  #pragma unroll
  for (int m=1; m<16; m<<=1){
    #pragma unroll
    for (int i=0;i<4;++i){
      if (MODE!=1){ z1a[i]+=__shfl_xor(z1a[i],m); z1b[i]+=__shfl_xor(z1b[i],m); }
      if (MODE>=1){ z2a[i]+=__shfl_xor(z2a[i],m); z2b[i]+=__shfl_xor(z2b[i],m); }
    }
  }
  if (c16 == 0){
    #pragma unroll
    for (int i=0;i<4;++i){
      int ra = rb+4*g+i, rb2 = rb+16+4*g+i;
      if (MODE!=1){ atomicAdd(&sum1[ra], z1a[i]); atomicAdd(&sum1[rb2], z1b[i]); }
      if (MODE>=1){ atomicAdd(&sum2[ra], z2a[i]); atomicAdd(&sum2[rb2], z2b[i]); }
    }
  }
}

__global__ __launch_bounds__(BLOCK)
void fin_ref1(const float* __restrict__ s1, const float* __restrict__ consts,
              float* __restrict__ dref, int n){
  int i = blockIdx.x*BLOCK + threadIdx.x;
  if (i>=n) return;
  float t = consts[1];
  dref[i] = exp2f(-t * log2f(s1[i]));      // s^(-t)
}

__global__ __launch_bounds__(BLOCK)
void fin_ref2(const float* __restrict__ s2, const float* __restrict__ dref,
              float* __restrict__ bref, int n){
  int i = blockIdx.x*BLOCK + threadIdx.x;
  if (i>=n) return;
  float d = dref[i];
  bref[i] = d / sqrtf(d*s2[i]);            // Dref*Dinv1ref
}

__global__ __launch_bounds__(BLOCK)
void fin_cross(const float* __restrict__ s1, const float* __restrict__ s2,
               const float* __restrict__ consts, float* __restrict__ ax, int n){
  int i = blockIdx.x*BLOCK + threadIdx.x;
  if (i>=n) return;
  float t = consts[1];
  float Dx = exp2f(-t * log2f(s1[i]));     // s1^(-t)
  ax[i] = Dx / sqrtf(Dx*s2[i]);            // Dx*Dinv1x
}

// Final W = ax[i] * w_ij * bref[j], same MFMA structure, direct stores.
__global__ __launch_bounds__(BLOCK)
void out_mfma(const u32* __restrict__ PX, const float* __restrict__ pax,
              const float* __restrict__ axv,
              const u32* __restrict__ PR, const float* __restrict__ pbr,
              const float* __restrict__ bref,
              float* __restrict__ W, int M)
{
  const int t=threadIdx.x, wv=t>>6, l=t&63, g=l>>4, c16=l&15;
  const int rb = (blockIdx.x*4 + wv)*32;
  const int j0 = blockIdx.y*CPCO;

  bf16x8 a0 = *reinterpret_cast<const bf16x8*>(PX + (size_t)(rb+c16)*16    + g*4);
  bf16x8 a1 = *reinterpret_cast<const bf16x8*>(PX + (size_t)(rb+16+c16)*16 + g*4);
  float pa0[4], pa1[4], ax0[4], ax1[4];
  float* wr0[4]; float* wr1[4];
  #pragma unroll
  for (int i=0;i<4;++i){
    int ra = rb+4*g+i, rb2 = rb+16+4*g+i;
    pa0[i]=pax[ra]; pa1[i]=pax[rb2];
    ax0[i]=axv[ra]; ax1[i]=axv[rb2];
    wr0[i] = W + (size_t)ra*M + c16;
    wr1[i] = W + (size_t)rb2*M + c16;
  }

  const u32* pb1 = PR + (size_t)(j0+c16)*16 + (g&1)*4;
  const float* ppb = pbr + j0 + c16;
  const float* pbb = bref + j0 + c16;

  #pragma unroll 2
  for (int tl=0; tl<CPCO/16; ++tl){
    bf16x8 b1 = *reinterpret_cast<const bf16x8*>(pb1);
    bf16x8 b2 = *reinterpret_cast<const bf16x8*>(pb1 + 8);
    float pb = *ppb;
    float bb = *pbb;

    f32x4 c0; c0[0]=pa0[0]+pb; c0[1]=pa0[1]+pb; c0[2]=pa0[2]+pb; c0[3]=pa0[3]+pb;
    c0 = __builtin_amdgcn_mfma_f32_16x16x32_bf16(a0,b1,c0,0,0,0);
    c0 = __builtin_amdgcn_mfma_f32_16x16x32_bf16(a0,b2,c0,0,0,0);
    f32x4 c1; c1[0]=pa1[0]+pb; c1[1]=pa1[1]+pb; c1[2]=pa1[2]+pb; c1[3]=pa1[3]+pb;
    c1 = __builtin_amdgcn_mfma_f32_16x16x32_bf16(a1,b1,c1,0,0,0);
    c1 = __builtin_amdgcn_mfma_f32_16x16x32_bf16(a1,b2,c1,0,0,0);

    const int off = j0 + tl*16;
    #pragma unroll
    for (int i=0;i<4;++i){
      wr0[i][off] = fexp2(c0[i])*(bb*ax0[i]);
      wr1[i][off] = fexp2(c1[i])*(bb*ax1[i]);
    }
    pb1 += 256; ppb += 16; pbb += 16;
  }
}

extern "C" void kernel_launch(void* const* d_in, const int* in_sizes, int n_in,
                              void* d_out, int out_size, void* d_ws, size_t ws_size,
                              hipStream_t stream) {
  const float* X  = (const float*)d_in[0];
  const float* R  = (const float*)d_in[1];
  const float* le = (const float*)d_in[2];
  const float* lt = (const float*)d_in[3];
  float* W = (float*)d_out;
  const int N = in_sizes[0]/16;
  const int M = in_sizes[1]/16;

  float* ws     = (float*)d_ws;
  float* consts = ws;              // 8
  float* pax    = consts + 8;      // N
  float* pbr    = pax + N;         // M
  float* dref   = pbr + M;         // M
  float* bref   = dref + M;        // M
  float* ax     = bref + M;        // N
  float* s1r    = ax + N;          // M (zeroed)
  float* s2r    = s1r + M;         // M (zeroed)
  float* s1x    = s2r + M;         // N (zeroed)
  float* s2x    = s1x + N;         // N (zeroed)
  u32*   PX     = (u32*)(s2x + N); // 16N words
  u32*   PR     = PX + (size_t)16*N; // 16M words

  consts_kernel<<<1, 64, 0, stream>>>(le, lt, consts);
  zero_kernel<<<(2*M+2*N + BLOCK-1)/BLOCK, BLOCK, 0, stream>>>(s1r, 2*M+2*N);
  prep_kernel<<<(N+M + BLOCK-1)/BLOCK, BLOCK, 0, stream>>>(X, R, consts, PX, PR, pax, pbr, N, M);

  dim3 gref(M/32/4, M/CPC);   // (64,16) for 8192
  dim3 gx  (N/32/4, M/CPC);
  // ref pass 1: Dref
  pass_mfma<0><<<gref, BLOCK, 0, stream>>>(PR, pbr, PR, pbr, dref, s1r, nullptr);
  fin_ref1<<<(M+BLOCK-1)/BLOCK, BLOCK, 0, stream>>>(s1r, consts, dref, M);
  // ref pass 2: bref = Dref*Dinv1ref
  pass_mfma<1><<<gref, BLOCK, 0, stream>>>(PR, pbr, PR, pbr, dref, nullptr, s2r);
  fin_ref2<<<(M+BLOCK-1)/BLOCK, BLOCK, 0, stream>>>(s2r, dref, bref, M);
  // cross pass: ax = Dx*Dinv1x
  pass_mfma<2><<<gx, BLOCK, 0, stream>>>(PX, pax, PR, pbr, dref, s1x, s2x);
  fin_cross<<<(N+BLOCK-1)/BLOCK, BLOCK, 0, stream>>>(s1x, s2x, consts, ax, N);
  // output
  dim3 go(N/32/4, M/CPCO);
  out_mfma<<<go, BLOCK, 0, stream>>>(PX, pax, ax, PR, pbr, bref, W, M);
}